// Round 14
// baseline (9062.463 us; speedup 1.0000x reference)
//
#include <hip/hip_runtime.h>
#include <hip/hip_bf16.h>
#include <cstdint>

typedef _Float16 half2v __attribute__((ext_vector_type(2)));
typedef short bf16x8 __attribute__((ext_vector_type(8)));
typedef float f32x4v __attribute__((ext_vector_type(4)));

#define DI __device__ __forceinline__

DI half2v bch(float f)    { return __builtin_bit_cast(half2v, f); }
DI half2v bcu(unsigned u) { return __builtin_bit_cast(half2v, u); }

DI float fdot2f(half2v a, half2v b, float c) {
#if __has_builtin(__builtin_amdgcn_fdot2)
  return __builtin_amdgcn_fdot2(a, b, c, false);
#else
  return c + (float)a[0] * (float)b[0] + (float)a[1] * (float)b[1];
#endif
}

DI unsigned short bf16rne(float f) {
  unsigned u = __float_as_uint(f);
  unsigned r = (u + 0x7fffu + ((u >> 16) & 1u)) >> 16;
  return (unsigned short)r;
}

DI unsigned int ordbits(float f) {
  unsigned int u = __float_as_uint(f);
  return (u & 0x80000000u) ? ~u : (u | 0x80000000u);
}

// ---------------- block reduce (256 threads, 4 waves) ----------------
DI float blockReduceSum(float v, float* sbuf) {
  for (int off = 32; off; off >>= 1) v += __shfl_xor(v, off, 64);
  int wid = threadIdx.x >> 6;
  if ((threadIdx.x & 63) == 0) sbuf[wid] = v;
  __syncthreads();
  float r = sbuf[0] + sbuf[1] + sbuf[2] + sbuf[3];
  __syncthreads();
  return r;
}

// ---------------- prep: weight repack + zeroing ----------------
__global__ __launch_bounds__(256) void prep_kernel(
    const float* __restrict__ conv_w, const float* __restrict__ w_hh,
    const float* __restrict__ w_ih, const float* __restrict__ b_ih,
    const float* __restrict__ b_hh, const float* __restrict__ emb,
    float* __restrict__ wT, _Float16* __restrict__ whhh,
    float* __restrict__ wihT, float* __restrict__ bias2,
    float* __restrict__ esq, int* __restrict__ counts)
{
  int idx = blockIdx.x * 256 + threadIdx.x;
  if (idx < 245760) {
    int c = idx % 768, rest = idx / 768;          // rest = ci*4+k
    wT[idx] = conv_w[c * 320 + rest];
  }
  int i1 = idx - 245760;
  if (i1 >= 0 && i1 < 262144) whhh[i1] = (_Float16)w_hh[i1];
  int i2 = idx - (245760 + 262144);
  if (i2 >= 0 && i2 < 65536) {
    int d = i2 >> 10, grow = i2 & 1023;
    wihT[i2] = w_ih[grow * 64 + d];
  }
  int i3 = idx - (245760 + 262144 + 65536);
  if (i3 >= 0 && i3 < 1024) bias2[i3] = b_ih[i3] + b_hh[i3];
  int i4 = idx - (245760 + 262144 + 65536 + 1024);
  if (i4 >= 0 && i4 < 512) {
    float s = 0.f;
    for (int d = 0; d < 64; ++d) { float v = emb[i4 * 64 + d]; s += v * v; }
    esq[i4] = s;
  }
  int i5 = idx - (245760 + 262144 + 65536 + 1024 + 512);
  if (i5 >= 0 && i5 < 512) counts[i5] = 0;
}

// ---------------- convert weights to bf16 (hi only) ----------------
__global__ __launch_bounds__(256) void wcvt_kernel(
    const float* __restrict__ w_hid, const float* __restrict__ w_out,
    const float* __restrict__ emb, unsigned short* __restrict__ Whi,
    unsigned short* __restrict__ Wzh, unsigned short* __restrict__ embh)
{
  int idx = blockIdx.x * 256 + threadIdx.x;
  if (idx < 2359296) Whi[idx] = bf16rne(w_hid[idx]);
  int i1 = idx - 2359296;
  if (i1 >= 0 && i1 < 49152) Wzh[i1] = bf16rne(w_out[i1]);
  int i2 = idx - (2359296 + 49152);
  if (i2 >= 0 && i2 < 32768) embh[i2] = bf16rne(emb[i2]);
}

// ---------------- conv1d k=4 s=2 p=1 as tiled GEMM-ish ----------------
__global__ __launch_bounds__(256) void conv_kernel(
    const float* __restrict__ mels, const float* __restrict__ wT,
    float* __restrict__ out)
{
  __shared__ float xs[80][68];
  const int bx = blockIdx.x;
  const int cblk = bx % 6;
  const int rb = bx / 6;
  const int b = rb >> 5;
  const int t0 = (rb & 31) << 5;
  const int tid = threadIdx.x;
  const int g0 = 2 * t0 - 1;
  for (int e = tid; e < 80 * 68; e += 256) {
    int ci = e / 68, ix = e % 68;
    int g = g0 + ix;
    float v = 0.f;
    if (ix < 67 && g >= 0 && g < 2048) v = mels[((size_t)b * 80 + ci) * 2048 + g];
    xs[ci][ix] = v;
  }
  __syncthreads();
  const int tc = tid & 31, tt = tid >> 5;
  const int c = cblk * 128 + tc * 4;
  float acc[4][4] = {};
  for (int ci = 0; ci < 80; ++ci) {
    float m[10];
#pragma unroll
    for (int r = 0; r < 10; ++r) m[r] = xs[ci][tt * 8 + r];
#pragma unroll
    for (int k = 0; k < 4; ++k) {
      float4 wv = *(const float4*)&wT[(size_t)(ci * 4 + k) * 768 + c];
#pragma unroll
      for (int i = 0; i < 4; ++i) {
        float mv = m[2 * i + k];
        acc[i][0] += mv * wv.x; acc[i][1] += mv * wv.y;
        acc[i][2] += mv * wv.z; acc[i][3] += mv * wv.w;
      }
    }
  }
#pragma unroll
  for (int i = 0; i < 4; ++i) {
    int tp = t0 + tt * 4 + i;
    float4 v = make_float4(acc[i][0], acc[i][1], acc[i][2], acc[i][3]);
    *(float4*)&out[((size_t)b * 1024 + tp) * 768 + c] = v;
  }
}

// ---------------- LayerNorm + ReLU -> bf16 (hi only) ----------------
__global__ __launch_bounds__(256) void ln_relu_kernel(
    const float* __restrict__ in, unsigned short* __restrict__ ohi,
    const float* __restrict__ gamma, const float* __restrict__ beta)
{
  __shared__ float sbuf[4];
  const int row = blockIdx.x, tid = threadIdx.x;
  const float* p = in + (size_t)row * 768;
  float v0 = p[tid], v1 = p[tid + 256], v2 = p[tid + 512];
  float s = blockReduceSum(v0 + v1 + v2, sbuf);
  float mean = s * (1.f / 768.f);
  float d0 = v0 - mean, d1 = v1 - mean, d2 = v2 - mean;
  float sq = blockReduceSum(d0 * d0 + d1 * d1 + d2 * d2, sbuf);
  float rstd = rsqrtf(sq * (1.f / 768.f) + 1e-5f);
  float y0 = fmaxf(d0 * rstd * gamma[tid]       + beta[tid],       0.f);
  float y1 = fmaxf(d1 * rstd * gamma[tid + 256] + beta[tid + 256], 0.f);
  float y2 = fmaxf(d2 * rstd * gamma[tid + 512] + beta[tid + 512], 0.f);
  unsigned short* qh = ohi + (size_t)row * 768;
  qh[tid] = bf16rne(y0); qh[tid + 256] = bf16rne(y1); qh[tid + 512] = bf16rne(y2);
}

// ---------------- bf16 MFMA GEMM: C = A W^T (hi only) -----------------------
__global__ __launch_bounds__(256) void mlp_gemm(
    const unsigned short* __restrict__ Ah, const unsigned short* __restrict__ Wh,
    float* __restrict__ C)
{
  __shared__ unsigned short As[128][40];   // 32 used + 8 pad (16B-aligned rows)
  __shared__ unsigned short Bs[128][40];
  const int tid = threadIdx.x;
  const int lane = tid & 63, wid = tid >> 6;
  const int wm = wid >> 1, wn = wid & 1;
  const int l15 = lane & 15, kg = lane >> 4;
  const size_t row0 = (size_t)blockIdx.y * 128;
  const int col0 = blockIdx.x * 128;
  f32x4v acc[4][4];
#pragma unroll
  for (int i = 0; i < 4; ++i)
#pragma unroll
    for (int j = 0; j < 4; ++j) acc[i][j] = (f32x4v){0.f, 0.f, 0.f, 0.f};
  for (int kt = 0; kt < 768; kt += 32) {
    __syncthreads();   // guard LDS overwrite vs previous iteration reads
#pragma unroll
    for (int it = 0; it < 2; ++it) {
      int sidx = tid + it * 256;           // 512 slots of 8 bf16 per tile
      int r = sidx >> 2, kc = (sidx & 3) << 3;
      *(uint4*)&As[r][kc] = *(const uint4*)&Ah[(row0 + r) * 768 + kt + kc];
      *(uint4*)&Bs[r][kc] = *(const uint4*)&Wh[(size_t)(col0 + r) * 768 + kt + kc];
    }
    __syncthreads();
    bf16x8 af[4], bfr[4];
#pragma unroll
    for (int mf = 0; mf < 4; ++mf)
      af[mf] = *(const bf16x8*)&As[wm * 64 + mf * 16 + l15][kg * 8];
#pragma unroll
    for (int nf = 0; nf < 4; ++nf)
      bfr[nf] = *(const bf16x8*)&Bs[wn * 64 + nf * 16 + l15][kg * 8];
#pragma unroll
    for (int mf = 0; mf < 4; ++mf)
#pragma unroll
      for (int nf = 0; nf < 4; ++nf)
        acc[mf][nf] = __builtin_amdgcn_mfma_f32_16x16x32_bf16(
            af[mf], bfr[nf], acc[mf][nf], 0, 0, 0);
  }
#pragma unroll
  for (int mf = 0; mf < 4; ++mf)
#pragma unroll
    for (int nf = 0; nf < 4; ++nf)
#pragma unroll
      for (int r = 0; r < 4; ++r)
        C[(row0 + wm * 64 + mf * 16 + kg * 4 + r) * 768 +
          col0 + wn * 64 + nf * 16 + l15] = acc[mf][nf][r];
}

// ---------------- fused tail: z = A4 @ Wz^T, dots vs emb, argmin, quant -----
__global__ __launch_bounds__(256) void ztail_kernel(
    const unsigned short* __restrict__ A4h, const unsigned short* __restrict__ Wzh,
    const unsigned short* __restrict__ embh, const float* __restrict__ esq,
    const float* __restrict__ emb, float* __restrict__ z_out,
    float* __restrict__ quant, int* __restrict__ counts,
    float* __restrict__ lossrow)
{
  __shared__ unsigned short As[128][40];            // 10240 B
  __shared__ unsigned short Ws[64][40];             // 5120 B
  __shared__ unsigned short zh[128][88];            // 22528 B
  __shared__ float zf[128][68];                     // 34816 B
  __shared__ unsigned short embs[128][88];          // 22528 B
  __shared__ unsigned long long best2[2][128];      // 2048 B
  __shared__ float esqs[512];                       // 2048 B
  const int tid = threadIdx.x;
  const int lane = tid & 63, wid = tid >> 6;
  const int wm = wid >> 1, wn = wid & 1;
  const int l15 = lane & 15, kg = lane >> 4;
  const size_t row0 = (size_t)blockIdx.x * 128;
  for (int i = tid; i < 512; i += 256) esqs[i] = esq[i];
  f32x4v zacc[4][2];
#pragma unroll
  for (int i = 0; i < 4; ++i)
#pragma unroll
    for (int j = 0; j < 2; ++j) zacc[i][j] = (f32x4v){0.f, 0.f, 0.f, 0.f};
  for (int kt = 0; kt < 768; kt += 32) {
    __syncthreads();
#pragma unroll
    for (int it = 0; it < 2; ++it) {
      int sidx = tid + it * 256;
      int r = sidx >> 2, kc = (sidx & 3) << 3;
      *(uint4*)&As[r][kc] = *(const uint4*)&A4h[(row0 + r) * 768 + kt + kc];
    }
    { int r = tid >> 2, kc = (tid & 3) << 3;
      *(uint4*)&Ws[r][kc] = *(const uint4*)&Wzh[r * 768 + kt + kc]; }
    __syncthreads();
    bf16x8 af[4], bfr[2];
#pragma unroll
    for (int mf = 0; mf < 4; ++mf)
      af[mf] = *(const bf16x8*)&As[wm * 64 + mf * 16 + l15][kg * 8];
#pragma unroll
    for (int nf = 0; nf < 2; ++nf)
      bfr[nf] = *(const bf16x8*)&Ws[wn * 32 + nf * 16 + l15][kg * 8];
#pragma unroll
    for (int mf = 0; mf < 4; ++mf)
#pragma unroll
      for (int nf = 0; nf < 2; ++nf)
        zacc[mf][nf] = __builtin_amdgcn_mfma_f32_16x16x32_bf16(
            af[mf], bfr[nf], zacc[mf][nf], 0, 0, 0);
  }
#pragma unroll
  for (int mf = 0; mf < 4; ++mf)
#pragma unroll
    for (int nf = 0; nf < 2; ++nf)
#pragma unroll
      for (int r = 0; r < 4; ++r) {
        float v = zacc[mf][nf][r];
        int rr = wm * 64 + mf * 16 + kg * 4 + r;
        int cc = wn * 32 + nf * 16 + l15;
        zf[rr][cc] = v;
        zh[rr][cc] = bf16rne(v);
        z_out[(row0 + rr) * 64 + cc] = v;
      }
  if (tid < 128) { best2[0][tid] = ~0ull; best2[1][tid] = ~0ull; }
  __syncthreads();
  for (int c0 = 0; c0 < 512; c0 += 128) {
    __syncthreads();
#pragma unroll
    for (int ii = 0; ii < 4; ++ii) {
      int s = tid * 4 + ii;
      int code = s >> 3, k = (s & 7) << 3;
      *(uint4*)&embs[code][k] = *(const uint4*)&embh[(size_t)(c0 + code) * 64 + k];
    }
    __syncthreads();
    bf16x8 af2[4][2], bf2[4][2];
#pragma unroll
    for (int mf = 0; mf < 4; ++mf)
#pragma unroll
      for (int kk = 0; kk < 2; ++kk)
        af2[mf][kk] = *(const bf16x8*)&zh[wm * 64 + mf * 16 + l15][kk * 32 + kg * 8];
#pragma unroll
    for (int nf = 0; nf < 4; ++nf)
#pragma unroll
      for (int kk = 0; kk < 2; ++kk)
        bf2[nf][kk] = *(const bf16x8*)&embs[wn * 64 + nf * 16 + l15][kk * 32 + kg * 8];
#pragma unroll
    for (int mf = 0; mf < 4; ++mf) {
      f32x4v dacc[4];
#pragma unroll
      for (int nf = 0; nf < 4; ++nf) {
        dacc[nf] = (f32x4v){0.f, 0.f, 0.f, 0.f};
        dacc[nf] = __builtin_amdgcn_mfma_f32_16x16x32_bf16(
            af2[mf][0], bf2[nf][0], dacc[nf], 0, 0, 0);
        dacc[nf] = __builtin_amdgcn_mfma_f32_16x16x32_bf16(
            af2[mf][1], bf2[nf][1], dacc[nf], 0, 0, 0);
      }
      unsigned long long rb0 = ~0ull, rb1 = ~0ull, rb2 = ~0ull, rb3 = ~0ull;
#pragma unroll
      for (int nf = 0; nf < 4; ++nf) {
        int code = c0 + wn * 64 + nf * 16 + l15;
        float ev = esqs[code];
        unsigned long long k0 = ((unsigned long long)ordbits(ev - 2.f * dacc[nf][0]) << 32) | (unsigned)code;
        unsigned long long k1 = ((unsigned long long)ordbits(ev - 2.f * dacc[nf][1]) << 32) | (unsigned)code;
        unsigned long long k2 = ((unsigned long long)ordbits(ev - 2.f * dacc[nf][2]) << 32) | (unsigned)code;
        unsigned long long k3 = ((unsigned long long)ordbits(ev - 2.f * dacc[nf][3]) << 32) | (unsigned)code;
        rb0 = k0 < rb0 ? k0 : rb0;  rb1 = k1 < rb1 ? k1 : rb1;
        rb2 = k2 < rb2 ? k2 : rb2;  rb3 = k3 < rb3 ? k3 : rb3;
      }
#pragma unroll
      for (int m = 1; m < 16; m <<= 1) {
        unsigned long long o;
        o = __shfl_xor(rb0, m, 64); rb0 = o < rb0 ? o : rb0;
        o = __shfl_xor(rb1, m, 64); rb1 = o < rb1 ? o : rb1;
        o = __shfl_xor(rb2, m, 64); rb2 = o < rb2 ? o : rb2;
        o = __shfl_xor(rb3, m, 64); rb3 = o < rb3 ? o : rb3;
      }
      if (l15 == 0) {
        int rbase = wm * 64 + mf * 16 + kg * 4;
        unsigned long long c;
        c = best2[wn][rbase + 0]; best2[wn][rbase + 0] = rb0 < c ? rb0 : c;
        c = best2[wn][rbase + 1]; best2[wn][rbase + 1] = rb1 < c ? rb1 : c;
        c = best2[wn][rbase + 2]; best2[wn][rbase + 2] = rb2 < c ? rb2 : c;
        c = best2[wn][rbase + 3]; best2[wn][rbase + 3] = rb3 < c ? rb3 : c;
      }
    }
  }
  __syncthreads();
  if (tid < 128) {
    unsigned long long a = best2[0][tid], b = best2[1][tid];
    best2[0][tid] = b < a ? b : a;
  }
  __syncthreads();
  {
    int rr = tid >> 1, hf = tid & 1;
    int bi = (int)(best2[0][rr] & 0xffffffffu);
    float ls = 0.f;
#pragma unroll
    for (int dd = 0; dd < 32; ++dd) {
      int d = hf * 32 + dd;
      float e = emb[(size_t)bi * 64 + d];
      quant[(row0 + rr) * 64 + d] = e;
      float df = zf[rr][d] - e;
      ls += df * df;
    }
    ls += __shfl_xor(ls, 1, 64);
    if (hf == 0) {
      lossrow[row0 + rr] = ls;
      atomicAdd(&counts[bi], 1);
    }
  }
}

// ---------------- loss + perplexity ----------------
__global__ __launch_bounds__(256) void finalize_kernel(
    const float* __restrict__ lossrow, const int* __restrict__ counts,
    float* __restrict__ loss_out, float* __restrict__ perp_out)
{
  __shared__ float sbuf[4];
  const int tid = threadIdx.x;
  float s = 0.f;
  for (int i = tid; i < 16384; i += 256) s += lossrow[i];
  s = blockReduceSum(s, sbuf);
  float t = 0.f;
  for (int e = tid; e < 512; e += 256) {
    float p = (float)counts[e] * (1.f / 16384.f);
    t += p * logf(p + 1e-10f);
  }
  t = blockReduceSum(t, sbuf);
  if (tid == 0) {
    *loss_out = 0.25f * s / (16384.f * 64.f);
    *perp_out = expf(-t);
  }
}

// ---------------- xg3[b][t][1024 gates natural order] = q @ w_ih^T + biases ---
__global__ __launch_bounds__(256) void xg_kernel(
    const float* __restrict__ q, const float* __restrict__ wihT,
    const float* __restrict__ bias2, float* __restrict__ xg3)
{
  __shared__ float qs[8][64];
  const int r0 = blockIdx.x * 8, tid = threadIdx.x;
  for (int e = tid; e < 512; e += 256)
    qs[e >> 6][e & 63] = q[(size_t)r0 * 64 + e];
  __syncthreads();
  float4 bias = *(const float4*)&bias2[tid * 4];
  float4 acc[8];
#pragma unroll
  for (int r = 0; r < 8; ++r) acc[r] = bias;
  for (int d = 0; d < 64; ++d) {
    float4 wv = *(const float4*)&wihT[d * 1024 + tid * 4];
#pragma unroll
    for (int r = 0; r < 8; ++r) {
      float qv = qs[r][d];
      acc[r].x += qv * wv.x; acc[r].y += qv * wv.y;
      acc[r].z += qv * wv.z; acc[r].w += qv * wv.w;
    }
  }
#pragma unroll
  for (int r = 0; r < 8; ++r)
    *(float4*)&xg3[(size_t)(r0 + r) * 1024 + tid * 4] = acc[r];
}

// ---------------- LSTM: aliasing-guaranteed streaming -----------------------
// R13 diagnosis: __restrict__ let LICM hoist in-loop weight loads -> demand
// 136 uint4-regs > 128 -> SCRATCH spill (32ms first-touch + 1.6us/step).
// Fix: whhh/cout are NOT __restrict__ -> the per-step cout store may alias
// whhh -> compiler MUST re-issue in-loop loads each iteration (true L2
// streaming, no scratch possible). Resident cut to 6 uint4/row (48 regs,
// demand ~80) so ~45 spare regs buffer the 34 streamed loads ~11-deep:
// stream ~(34/11)*300cy ~ 900cy overlapping 1024cy VALU. LSTM was never
// L2-BW-bound (16 blocks = 2 CU/XCD, 4.3TB/s/XCD available) -- it is
// load-PIPELINING bound; registers buy depth, not residency.
#define W6(M) M(0) M(1) M(2) M(3) M(4) M(5)
#define DECLW(J) uint4 wa##J = pA[J]; uint4 wb##J = pB[J];
#define DOTR(J) { float4 h4 = hb4[J]; \
  a0 = fdot2f(bcu(wa##J.x), bch(h4.x), a0); b0 = fdot2f(bcu(wb##J.x), bch(h4.x), b0); \
  a1 = fdot2f(bcu(wa##J.y), bch(h4.y), a1); b1 = fdot2f(bcu(wb##J.y), bch(h4.y), b1); \
  a0 = fdot2f(bcu(wa##J.z), bch(h4.z), a0); b0 = fdot2f(bcu(wb##J.z), bch(h4.z), b0); \
  a1 = fdot2f(bcu(wa##J.w), bch(h4.w), a1); b1 = fdot2f(bcu(wb##J.w), bch(h4.w), b1); }

__global__
__attribute__((amdgpu_flat_work_group_size(512, 512), amdgpu_waves_per_eu(2, 2)))
void lstm_kernel(
    const float* __restrict__ xg3, const _Float16* whhh, float* cout)
{
  __shared__ unsigned wlds[1024 * 36];            // 147456 B
  __shared__ __align__(16) _Float16 hb[256];      // 512 B
  __shared__ float gbuf[512];                     // 2048 B
  const int tid = threadIdx.x;
  const int b = blockIdx.x;
  const int jloc = tid & 255;
  const int half = tid >> 8;
  const int rA = half * 256 + jloc;       // half0: i-row, half1: f-row
  const int rB = 512 + half * 256 + jloc; // half0: g-row, half1: o-row
  // stage LDS: dwords [92,128) of each row
  {
    const unsigned* wsrc = (const unsigned*)whhh;
    for (int idx = tid; idx < 1024 * 36; idx += 512) {
      int row = idx / 36, kp = idx - row * 36;
      wlds[row * 36 + kp] = wsrc[row * 128 + 92 + kp];
    }
  }
  if (tid < 256) hb[tid] = (_Float16)0.f;
  const uint4* pA = (const uint4*)(whhh + (size_t)rA * 256);
  const uint4* pB = (const uint4*)(whhh + (size_t)rB * 256);
  W6(DECLW)                               // dwords [0,24): resident (pre-loop)
  const size_t bT = (size_t)b * 1024;
  const int rA36 = rA * 36, rB36 = rB * 36;
  float cst = 0.f;
  float xgA = xg3[bT * 1024 + rA];
  float xgB = xg3[bT * 1024 + rB];
  __syncthreads();
  for (int t = 0; t < 1024; ++t) {
    float nxA = 0.f, nxB = 0.f;
    if (t < 1023) {
      nxA = xg3[(bT + t + 1) * 1024 + rA];
      nxB = xg3[(bT + t + 1) * 1024 + rB];
    }
    float a0 = 0.f, a1 = 0.f, b0 = 0.f, b1 = 0.f;
    const float4* hb4 = (const float4*)hb;
    W6(DOTR)
    // streamed: dwords [24,92) -> 17 uint4 per row, re-loaded every step
    // (cout-store aliasing forbids hoisting; loads pipeline within the step)
#pragma unroll
    for (int j = 0; j < 17; ++j) {
      uint4 wa = pA[6 + j];
      uint4 wb = pB[6 + j];
      float4 h4 = hb4[6 + j];
      a0 = fdot2f(bcu(wa.x), bch(h4.x), a0); b0 = fdot2f(bcu(wb.x), bch(h4.x), b0);
      a1 = fdot2f(bcu(wa.y), bch(h4.y), a1); b1 = fdot2f(bcu(wb.y), bch(h4.y), b1);
      a0 = fdot2f(bcu(wa.z), bch(h4.z), a0); b0 = fdot2f(bcu(wb.z), bch(h4.z), b0);
      a1 = fdot2f(bcu(wa.w), bch(h4.w), a1); b1 = fdot2f(bcu(wb.w), bch(h4.w), b1);
    }
    // LDS section: dwords [92,128) -> 9 uint4 per row
#pragma unroll
    for (int j = 0; j < 9; ++j) {
      float4 h4 = hb4[23 + j];
      uint4 wa = *(const uint4*)&wlds[rA36 + 4 * j];
      uint4 wb = *(const uint4*)&wlds[rB36 + 4 * j];
      a0 = fdot2f(bcu(wa.x), bch(h4.x), a0); b0 = fdot2f(bcu(wb.x), bch(h4.x), b0);
      a1 = fdot2f(bcu(wa.y), bch(h4.y), a1); b1 = fdot2f(bcu(wb.y), bch(h4.y), b1);
      a0 = fdot2f(bcu(wa.z), bch(h4.z), a0); b0 = fdot2f(bcu(wb.z), bch(h4.z), b0);
      a1 = fdot2f(bcu(wa.w), bch(h4.w), a1); b1 = fdot2f(bcu(wb.w), bch(h4.w), b1);
    }
    float gA = a0 + a1 + xgA;   // half0: i-gate   half1: f-gate
    float gB = b0 + b1 + xgB;   // half0: g-gate   half1: o-gate
    if (half) { gbuf[jloc] = gA; gbuf[256 + jloc] = gB; }
    __syncthreads();
    if (!half) {
      float gf = gbuf[jloc], go = gbuf[256 + jloc];
      float si = 1.f / (1.f + __expf(-gA));
      float sf = 1.f / (1.f + __expf(-gf));
      float so = 1.f / (1.f + __expf(-go));
      float tg = 1.f - 2.f / (1.f + __expf(2.f * gB));
      cst = sf * cst + si * tg;
      float tc = 1.f - 2.f / (1.f + __expf(2.f * cst));
      float h = so * tc;
      cout[(bT + t) * 256 + jloc] = h;
      hb[jloc] = (_Float16)h;
    }
    __syncthreads();
    xgA = nxA; xgB = nxB;
  }
}

// ---------------- launch ----------------
extern "C" void kernel_launch(void* const* d_in, const int* in_sizes, int n_in,
                              void* d_out, int out_size, void* d_ws, size_t ws_size,
                              hipStream_t stream)
{
  const float* mels   = (const float*)d_in[0];
  const float* conv_w = (const float*)d_in[1];
  const float* ln_g   = (const float*)d_in[2];
  const float* ln_b   = (const float*)d_in[3];
  const float* w_hid  = (const float*)d_in[4];
  const float* w_out  = (const float*)d_in[5];
  const float* emb    = (const float*)d_in[6];
  const float* w_ih   = (const float*)d_in[7];
  const float* w_hh   = (const float*)d_in[8];
  const float* b_ih   = (const float*)d_in[9];
  const float* b_hh   = (const float*)d_in[10];

  float* out = (float*)d_out;
  float* q_out   = out;                 // [16,1024,64]
  float* c_out   = out + 1048576;       // [16,1024,256]
  float* z_out   = out + 5242880;       // [16,1024,64]
  float* loss_out = out + 6291456;
  float* perp_out = out + 6291457;

  char* ws = (char*)d_ws;
  float*  hA    = (float*)(ws + 0);            // 50331648 B (f32 activations)
  unsigned short* Ahi = (unsigned short*)(ws + 50331648);   // 25165824 B
  float*  xg3   = (float*)(ws + 50331648);     // alias Ahi (dead after ztail)
  char* wsw = ws + 117440512;
  float*    wT     = (float*)(wsw);                        // 983040 B
  _Float16* whhh   = (_Float16*)(wsw + 983040);            // 524288 B
  float*    wihT   = (float*)(wsw + 1507328);              // 262144 B
  float*    bias2  = (float*)(wsw + 1769472);              // 4096 B
  float*    esq    = (float*)(wsw + 1773568);              // 2048 B
  int*      counts = (int*)  (wsw + 1775616);              // 2048 B
  float*    lossrow= (float*)(wsw + 1777664);              // 65536 B
  unsigned short* Whi  = (unsigned short*)((char*)d_out + 4194304);
  unsigned short* Wzh  = (unsigned short*)((char*)d_out + 4194304 + 4718592);
  unsigned short* embh = (unsigned short*)((char*)d_out + 4194304 + 4718592 + 98304);
  if (ws_size < 119283712u) return;  // insufficient scratch: fail visibly

  prep_kernel<<<2248, 256, 0, stream>>>(conv_w, w_hh, w_ih, b_ih, b_hh, emb,
                                        wT, whhh, wihT, bias2, esq, counts);
  wcvt_kernel<<<9536, 256, 0, stream>>>(w_hid, w_out, emb, Whi, Wzh, embh);
  conv_kernel<<<3072, 256, 0, stream>>>(mels, wT, hA);
  for (int l = 0; l < 4; ++l) {
    ln_relu_kernel<<<16384, 256, 0, stream>>>(hA, Ahi, ln_g + l * 768, ln_b + l * 768);
    mlp_gemm<<<dim3(6, 128), 256, 0, stream>>>(
        Ahi, Whi + (size_t)l * 589824, hA);
  }
  ln_relu_kernel<<<16384, 256, 0, stream>>>(hA, Ahi, ln_g + 4 * 768, ln_b + 4 * 768);
  ztail_kernel<<<128, 256, 0, stream>>>(Ahi, Wzh, embh, esq, emb,
                                        z_out, q_out, counts, lossrow);
  finalize_kernel<<<1, 256, 0, stream>>>(lossrow, counts, loss_out, perp_out);
  xg_kernel<<<2048, 256, 0, stream>>>(q_out, wihT, bias2, xg3);
  lstm_kernel<<<16, 512, 0, stream>>>(xg3, whhh, c_out);
}

// Round 15
// 6359.626 us; speedup vs baseline: 1.4250x; 1.4250x over previous
//
#include <hip/hip_runtime.h>
#include <hip/hip_bf16.h>
#include <cstdint>

typedef _Float16 half2v __attribute__((ext_vector_type(2)));
typedef short bf16x8 __attribute__((ext_vector_type(8)));
typedef float f32x4v __attribute__((ext_vector_type(4)));

#define DI __device__ __forceinline__

DI half2v bch(float f)    { return __builtin_bit_cast(half2v, f); }
DI half2v bcu(unsigned u) { return __builtin_bit_cast(half2v, u); }

DI float fdot2f(half2v a, half2v b, float c) {
#if __has_builtin(__builtin_amdgcn_fdot2)
  return __builtin_amdgcn_fdot2(a, b, c, false);
#else
  return c + (float)a[0] * (float)b[0] + (float)a[1] * (float)b[1];
#endif
}

DI unsigned short bf16rne(float f) {
  unsigned u = __float_as_uint(f);
  unsigned r = (u + 0x7fffu + ((u >> 16) & 1u)) >> 16;
  return (unsigned short)r;
}

DI unsigned int ordbits(float f) {
  unsigned int u = __float_as_uint(f);
  return (u & 0x80000000u) ? ~u : (u | 0x80000000u);
}

// ---------------- block reduce (256 threads, 4 waves) ----------------
DI float blockReduceSum(float v, float* sbuf) {
  for (int off = 32; off; off >>= 1) v += __shfl_xor(v, off, 64);
  int wid = threadIdx.x >> 6;
  if ((threadIdx.x & 63) == 0) sbuf[wid] = v;
  __syncthreads();
  float r = sbuf[0] + sbuf[1] + sbuf[2] + sbuf[3];
  __syncthreads();
  return r;
}

// ---------------- prep: weight repack + zeroing ----------------
__global__ __launch_bounds__(256) void prep_kernel(
    const float* __restrict__ conv_w, const float* __restrict__ w_hh,
    const float* __restrict__ w_ih, const float* __restrict__ b_ih,
    const float* __restrict__ b_hh, const float* __restrict__ emb,
    float* __restrict__ wT, _Float16* __restrict__ whhh,
    float* __restrict__ wihT, float* __restrict__ bias2,
    float* __restrict__ esq, int* __restrict__ counts)
{
  int idx = blockIdx.x * 256 + threadIdx.x;
  if (idx < 245760) {
    int c = idx % 768, rest = idx / 768;          // rest = ci*4+k
    wT[idx] = conv_w[c * 320 + rest];
  }
  int i1 = idx - 245760;
  if (i1 >= 0 && i1 < 262144) whhh[i1] = (_Float16)w_hh[i1];
  int i2 = idx - (245760 + 262144);
  if (i2 >= 0 && i2 < 65536) {
    int d = i2 >> 10, grow = i2 & 1023;
    wihT[i2] = w_ih[grow * 64 + d];
  }
  int i3 = idx - (245760 + 262144 + 65536);
  if (i3 >= 0 && i3 < 1024) bias2[i3] = b_ih[i3] + b_hh[i3];
  int i4 = idx - (245760 + 262144 + 65536 + 1024);
  if (i4 >= 0 && i4 < 512) {
    float s = 0.f;
    for (int d = 0; d < 64; ++d) { float v = emb[i4 * 64 + d]; s += v * v; }
    esq[i4] = s;
  }
  int i5 = idx - (245760 + 262144 + 65536 + 1024 + 512);
  if (i5 >= 0 && i5 < 512) counts[i5] = 0;
}

// ---------------- convert weights to bf16 (hi only) ----------------
__global__ __launch_bounds__(256) void wcvt_kernel(
    const float* __restrict__ w_hid, const float* __restrict__ w_out,
    const float* __restrict__ emb, unsigned short* __restrict__ Whi,
    unsigned short* __restrict__ Wzh, unsigned short* __restrict__ embh)
{
  int idx = blockIdx.x * 256 + threadIdx.x;
  if (idx < 2359296) Whi[idx] = bf16rne(w_hid[idx]);
  int i1 = idx - 2359296;
  if (i1 >= 0 && i1 < 49152) Wzh[i1] = bf16rne(w_out[i1]);
  int i2 = idx - (2359296 + 49152);
  if (i2 >= 0 && i2 < 32768) embh[i2] = bf16rne(emb[i2]);
}

// ---------------- conv1d k=4 s=2 p=1 as tiled GEMM-ish ----------------
__global__ __launch_bounds__(256) void conv_kernel(
    const float* __restrict__ mels, const float* __restrict__ wT,
    float* __restrict__ out)
{
  __shared__ float xs[80][68];
  const int bx = blockIdx.x;
  const int cblk = bx % 6;
  const int rb = bx / 6;
  const int b = rb >> 5;
  const int t0 = (rb & 31) << 5;
  const int tid = threadIdx.x;
  const int g0 = 2 * t0 - 1;
  for (int e = tid; e < 80 * 68; e += 256) {
    int ci = e / 68, ix = e % 68;
    int g = g0 + ix;
    float v = 0.f;
    if (ix < 67 && g >= 0 && g < 2048) v = mels[((size_t)b * 80 + ci) * 2048 + g];
    xs[ci][ix] = v;
  }
  __syncthreads();
  const int tc = tid & 31, tt = tid >> 5;
  const int c = cblk * 128 + tc * 4;
  float acc[4][4] = {};
  for (int ci = 0; ci < 80; ++ci) {
    float m[10];
#pragma unroll
    for (int r = 0; r < 10; ++r) m[r] = xs[ci][tt * 8 + r];
#pragma unroll
    for (int k = 0; k < 4; ++k) {
      float4 wv = *(const float4*)&wT[(size_t)(ci * 4 + k) * 768 + c];
#pragma unroll
      for (int i = 0; i < 4; ++i) {
        float mv = m[2 * i + k];
        acc[i][0] += mv * wv.x; acc[i][1] += mv * wv.y;
        acc[i][2] += mv * wv.z; acc[i][3] += mv * wv.w;
      }
    }
  }
#pragma unroll
  for (int i = 0; i < 4; ++i) {
    int tp = t0 + tt * 4 + i;
    float4 v = make_float4(acc[i][0], acc[i][1], acc[i][2], acc[i][3]);
    *(float4*)&out[((size_t)b * 1024 + tp) * 768 + c] = v;
  }
}

// ---------------- LayerNorm + ReLU -> bf16 (hi only) ----------------
__global__ __launch_bounds__(256) void ln_relu_kernel(
    const float* __restrict__ in, unsigned short* __restrict__ ohi,
    const float* __restrict__ gamma, const float* __restrict__ beta)
{
  __shared__ float sbuf[4];
  const int row = blockIdx.x, tid = threadIdx.x;
  const float* p = in + (size_t)row * 768;
  float v0 = p[tid], v1 = p[tid + 256], v2 = p[tid + 512];
  float s = blockReduceSum(v0 + v1 + v2, sbuf);
  float mean = s * (1.f / 768.f);
  float d0 = v0 - mean, d1 = v1 - mean, d2 = v2 - mean;
  float sq = blockReduceSum(d0 * d0 + d1 * d1 + d2 * d2, sbuf);
  float rstd = rsqrtf(sq * (1.f / 768.f) + 1e-5f);
  float y0 = fmaxf(d0 * rstd * gamma[tid]       + beta[tid],       0.f);
  float y1 = fmaxf(d1 * rstd * gamma[tid + 256] + beta[tid + 256], 0.f);
  float y2 = fmaxf(d2 * rstd * gamma[tid + 512] + beta[tid + 512], 0.f);
  unsigned short* qh = ohi + (size_t)row * 768;
  qh[tid] = bf16rne(y0); qh[tid + 256] = bf16rne(y1); qh[tid + 512] = bf16rne(y2);
}

// ---------------- bf16 MFMA GEMM: C = A W^T (hi only) -----------------------
__global__ __launch_bounds__(256) void mlp_gemm(
    const unsigned short* __restrict__ Ah, const unsigned short* __restrict__ Wh,
    float* __restrict__ C)
{
  __shared__ unsigned short As[128][40];   // 32 used + 8 pad (16B-aligned rows)
  __shared__ unsigned short Bs[128][40];
  const int tid = threadIdx.x;
  const int lane = tid & 63, wid = tid >> 6;
  const int wm = wid >> 1, wn = wid & 1;
  const int l15 = lane & 15, kg = lane >> 4;
  const size_t row0 = (size_t)blockIdx.y * 128;
  const int col0 = blockIdx.x * 128;
  f32x4v acc[4][4];
#pragma unroll
  for (int i = 0; i < 4; ++i)
#pragma unroll
    for (int j = 0; j < 4; ++j) acc[i][j] = (f32x4v){0.f, 0.f, 0.f, 0.f};
  for (int kt = 0; kt < 768; kt += 32) {
    __syncthreads();   // guard LDS overwrite vs previous iteration reads
#pragma unroll
    for (int it = 0; it < 2; ++it) {
      int sidx = tid + it * 256;           // 512 slots of 8 bf16 per tile
      int r = sidx >> 2, kc = (sidx & 3) << 3;
      *(uint4*)&As[r][kc] = *(const uint4*)&Ah[(row0 + r) * 768 + kt + kc];
      *(uint4*)&Bs[r][kc] = *(const uint4*)&Wh[(size_t)(col0 + r) * 768 + kt + kc];
    }
    __syncthreads();
    bf16x8 af[4], bfr[4];
#pragma unroll
    for (int mf = 0; mf < 4; ++mf)
      af[mf] = *(const bf16x8*)&As[wm * 64 + mf * 16 + l15][kg * 8];
#pragma unroll
    for (int nf = 0; nf < 4; ++nf)
      bfr[nf] = *(const bf16x8*)&Bs[wn * 64 + nf * 16 + l15][kg * 8];
#pragma unroll
    for (int mf = 0; mf < 4; ++mf)
#pragma unroll
      for (int nf = 0; nf < 4; ++nf)
        acc[mf][nf] = __builtin_amdgcn_mfma_f32_16x16x32_bf16(
            af[mf], bfr[nf], acc[mf][nf], 0, 0, 0);
  }
#pragma unroll
  for (int mf = 0; mf < 4; ++mf)
#pragma unroll
    for (int nf = 0; nf < 4; ++nf)
#pragma unroll
      for (int r = 0; r < 4; ++r)
        C[(row0 + wm * 64 + mf * 16 + kg * 4 + r) * 768 +
          col0 + wn * 64 + nf * 16 + l15] = acc[mf][nf][r];
}

// ---------------- fused tail: z = A4 @ Wz^T, dots vs emb, argmin, quant -----
__global__ __launch_bounds__(256) void ztail_kernel(
    const unsigned short* __restrict__ A4h, const unsigned short* __restrict__ Wzh,
    const unsigned short* __restrict__ embh, const float* __restrict__ esq,
    const float* __restrict__ emb, float* __restrict__ z_out,
    float* __restrict__ quant, int* __restrict__ counts,
    float* __restrict__ lossrow)
{
  __shared__ unsigned short As[128][40];            // 10240 B
  __shared__ unsigned short Ws[64][40];             // 5120 B
  __shared__ unsigned short zh[128][88];            // 22528 B
  __shared__ float zf[128][68];                     // 34816 B
  __shared__ unsigned short embs[128][88];          // 22528 B
  __shared__ unsigned long long best2[2][128];      // 2048 B
  __shared__ float esqs[512];                       // 2048 B
  const int tid = threadIdx.x;
  const int lane = tid & 63, wid = tid >> 6;
  const int wm = wid >> 1, wn = wid & 1;
  const int l15 = lane & 15, kg = lane >> 4;
  const size_t row0 = (size_t)blockIdx.x * 128;
  for (int i = tid; i < 512; i += 256) esqs[i] = esq[i];
  f32x4v zacc[4][2];
#pragma unroll
  for (int i = 0; i < 4; ++i)
#pragma unroll
    for (int j = 0; j < 2; ++j) zacc[i][j] = (f32x4v){0.f, 0.f, 0.f, 0.f};
  for (int kt = 0; kt < 768; kt += 32) {
    __syncthreads();
#pragma unroll
    for (int it = 0; it < 2; ++it) {
      int sidx = tid + it * 256;
      int r = sidx >> 2, kc = (sidx & 3) << 3;
      *(uint4*)&As[r][kc] = *(const uint4*)&A4h[(row0 + r) * 768 + kt + kc];
    }
    { int r = tid >> 2, kc = (tid & 3) << 3;
      *(uint4*)&Ws[r][kc] = *(const uint4*)&Wzh[r * 768 + kt + kc]; }
    __syncthreads();
    bf16x8 af[4], bfr[2];
#pragma unroll
    for (int mf = 0; mf < 4; ++mf)
      af[mf] = *(const bf16x8*)&As[wm * 64 + mf * 16 + l15][kg * 8];
#pragma unroll
    for (int nf = 0; nf < 2; ++nf)
      bfr[nf] = *(const bf16x8*)&Ws[wn * 32 + nf * 16 + l15][kg * 8];
#pragma unroll
    for (int mf = 0; mf < 4; ++mf)
#pragma unroll
      for (int nf = 0; nf < 2; ++nf)
        zacc[mf][nf] = __builtin_amdgcn_mfma_f32_16x16x32_bf16(
            af[mf], bfr[nf], zacc[mf][nf], 0, 0, 0);
  }
#pragma unroll
  for (int mf = 0; mf < 4; ++mf)
#pragma unroll
    for (int nf = 0; nf < 2; ++nf)
#pragma unroll
      for (int r = 0; r < 4; ++r) {
        float v = zacc[mf][nf][r];
        int rr = wm * 64 + mf * 16 + kg * 4 + r;
        int cc = wn * 32 + nf * 16 + l15;
        zf[rr][cc] = v;
        zh[rr][cc] = bf16rne(v);
        z_out[(row0 + rr) * 64 + cc] = v;
      }
  if (tid < 128) { best2[0][tid] = ~0ull; best2[1][tid] = ~0ull; }
  __syncthreads();
  for (int c0 = 0; c0 < 512; c0 += 128) {
    __syncthreads();
#pragma unroll
    for (int ii = 0; ii < 4; ++ii) {
      int s = tid * 4 + ii;
      int code = s >> 3, k = (s & 7) << 3;
      *(uint4*)&embs[code][k] = *(const uint4*)&embh[(size_t)(c0 + code) * 64 + k];
    }
    __syncthreads();
    bf16x8 af2[4][2], bf2[4][2];
#pragma unroll
    for (int mf = 0; mf < 4; ++mf)
#pragma unroll
      for (int kk = 0; kk < 2; ++kk)
        af2[mf][kk] = *(const bf16x8*)&zh[wm * 64 + mf * 16 + l15][kk * 32 + kg * 8];
#pragma unroll
    for (int nf = 0; nf < 4; ++nf)
#pragma unroll
      for (int kk = 0; kk < 2; ++kk)
        bf2[nf][kk] = *(const bf16x8*)&embs[wn * 64 + nf * 16 + l15][kk * 32 + kg * 8];
#pragma unroll
    for (int mf = 0; mf < 4; ++mf) {
      f32x4v dacc[4];
#pragma unroll
      for (int nf = 0; nf < 4; ++nf) {
        dacc[nf] = (f32x4v){0.f, 0.f, 0.f, 0.f};
        dacc[nf] = __builtin_amdgcn_mfma_f32_16x16x32_bf16(
            af2[mf][0], bf2[nf][0], dacc[nf], 0, 0, 0);
        dacc[nf] = __builtin_amdgcn_mfma_f32_16x16x32_bf16(
            af2[mf][1], bf2[nf][1], dacc[nf], 0, 0, 0);
      }
      unsigned long long rb0 = ~0ull, rb1 = ~0ull, rb2 = ~0ull, rb3 = ~0ull;
#pragma unroll
      for (int nf = 0; nf < 4; ++nf) {
        int code = c0 + wn * 64 + nf * 16 + l15;
        float ev = esqs[code];
        unsigned long long k0 = ((unsigned long long)ordbits(ev - 2.f * dacc[nf][0]) << 32) | (unsigned)code;
        unsigned long long k1 = ((unsigned long long)ordbits(ev - 2.f * dacc[nf][1]) << 32) | (unsigned)code;
        unsigned long long k2 = ((unsigned long long)ordbits(ev - 2.f * dacc[nf][2]) << 32) | (unsigned)code;
        unsigned long long k3 = ((unsigned long long)ordbits(ev - 2.f * dacc[nf][3]) << 32) | (unsigned)code;
        rb0 = k0 < rb0 ? k0 : rb0;  rb1 = k1 < rb1 ? k1 : rb1;
        rb2 = k2 < rb2 ? k2 : rb2;  rb3 = k3 < rb3 ? k3 : rb3;
      }
#pragma unroll
      for (int m = 1; m < 16; m <<= 1) {
        unsigned long long o;
        o = __shfl_xor(rb0, m, 64); rb0 = o < rb0 ? o : rb0;
        o = __shfl_xor(rb1, m, 64); rb1 = o < rb1 ? o : rb1;
        o = __shfl_xor(rb2, m, 64); rb2 = o < rb2 ? o : rb2;
        o = __shfl_xor(rb3, m, 64); rb3 = o < rb3 ? o : rb3;
      }
      if (l15 == 0) {
        int rbase = wm * 64 + mf * 16 + kg * 4;
        unsigned long long c;
        c = best2[wn][rbase + 0]; best2[wn][rbase + 0] = rb0 < c ? rb0 : c;
        c = best2[wn][rbase + 1]; best2[wn][rbase + 1] = rb1 < c ? rb1 : c;
        c = best2[wn][rbase + 2]; best2[wn][rbase + 2] = rb2 < c ? rb2 : c;
        c = best2[wn][rbase + 3]; best2[wn][rbase + 3] = rb3 < c ? rb3 : c;
      }
    }
  }
  __syncthreads();
  if (tid < 128) {
    unsigned long long a = best2[0][tid], b = best2[1][tid];
    best2[0][tid] = b < a ? b : a;
  }
  __syncthreads();
  {
    int rr = tid >> 1, hf = tid & 1;
    int bi = (int)(best2[0][rr] & 0xffffffffu);
    float ls = 0.f;
#pragma unroll
    for (int dd = 0; dd < 32; ++dd) {
      int d = hf * 32 + dd;
      float e = emb[(size_t)bi * 64 + d];
      quant[(row0 + rr) * 64 + d] = e;
      float df = zf[rr][d] - e;
      ls += df * df;
    }
    ls += __shfl_xor(ls, 1, 64);
    if (hf == 0) {
      lossrow[row0 + rr] = ls;
      atomicAdd(&counts[bi], 1);
    }
  }
}

// ---------------- loss + perplexity ----------------
__global__ __launch_bounds__(256) void finalize_kernel(
    const float* __restrict__ lossrow, const int* __restrict__ counts,
    float* __restrict__ loss_out, float* __restrict__ perp_out)
{
  __shared__ float sbuf[4];
  const int tid = threadIdx.x;
  float s = 0.f;
  for (int i = tid; i < 16384; i += 256) s += lossrow[i];
  s = blockReduceSum(s, sbuf);
  float t = 0.f;
  for (int e = tid; e < 512; e += 256) {
    float p = (float)counts[e] * (1.f / 16384.f);
    t += p * logf(p + 1e-10f);
  }
  t = blockReduceSum(t, sbuf);
  if (tid == 0) {
    *loss_out = 0.25f * s / (16384.f * 64.f);
    *perp_out = expf(-t);
  }
}

// ---------------- xg3[b][t][1024 gates natural order] = q @ w_ih^T + biases ---
__global__ __launch_bounds__(256) void xg_kernel(
    const float* __restrict__ q, const float* __restrict__ wihT,
    const float* __restrict__ bias2, float* __restrict__ xg3)
{
  __shared__ float qs[8][64];
  const int r0 = blockIdx.x * 8, tid = threadIdx.x;
  for (int e = tid; e < 512; e += 256)
    qs[e >> 6][e & 63] = q[(size_t)r0 * 64 + e];
  __syncthreads();
  float4 bias = *(const float4*)&bias2[tid * 4];
  float4 acc[8];
#pragma unroll
  for (int r = 0; r < 8; ++r) acc[r] = bias;
  for (int d = 0; d < 64; ++d) {
    float4 wv = *(const float4*)&wihT[d * 1024 + tid * 4];
#pragma unroll
    for (int r = 0; r < 8; ++r) {
      float qv = qs[r][d];
      acc[r].x += qv * wv.x; acc[r].y += qv * wv.y;
      acc[r].z += qv * wv.z; acc[r].w += qv * wv.w;
    }
  }
#pragma unroll
  for (int r = 0; r < 8; ++r)
    *(float4*)&xg3[(size_t)(r0 + r) * 1024 + tid * 4] = acc[r];
}

// ---------------- LSTM: fence-enforced resident/streamed split --------------
// FINAL LSTM experiment (pre-committed). Mechanism ledger:
//   R13 (__restrict__, no fence): LICM hoisted streamed loads -> demand 214
//     -> scratch spill (32ms first-touch) + 1600us steady.
//   R14 (no __restrict__): store->load ordering serialized pipeline (8.5us).
//   R15 (this): __restrict__ RESTORED + asm volatile memory clobber in-loop:
//     - streamed loads can't be hoisted (LICM illegal across clobber)
//     - resident pre-loop loads can't be REMAT'd across clobber -> truly
//       resident (demand 24 uint4 = 96 + ~28 working = ~124 <= 128, fits)
//     - no ordering imposed among loads within an iteration -> pipelining OK
// Split per gate-row: [0,48) resident, [48,92) streamed, [92,128) LDS.
#define W12(M) M(0) M(1) M(2) M(3) M(4) M(5) M(6) M(7) M(8) M(9) M(10) M(11)
#define DECLW(J) uint4 wa##J = pA[J]; uint4 wb##J = pB[J];
#define DOTR(J) { float4 h4 = hb4[J]; \
  a0 = fdot2f(bcu(wa##J.x), bch(h4.x), a0); b0 = fdot2f(bcu(wb##J.x), bch(h4.x), b0); \
  a1 = fdot2f(bcu(wa##J.y), bch(h4.y), a1); b1 = fdot2f(bcu(wb##J.y), bch(h4.y), b1); \
  a0 = fdot2f(bcu(wa##J.z), bch(h4.z), a0); b0 = fdot2f(bcu(wb##J.z), bch(h4.z), b0); \
  a1 = fdot2f(bcu(wa##J.w), bch(h4.w), a1); b1 = fdot2f(bcu(wb##J.w), bch(h4.w), b1); }

__global__
__attribute__((amdgpu_flat_work_group_size(512, 512), amdgpu_waves_per_eu(2, 2)))
void lstm_kernel(
    const float* __restrict__ xg3, const _Float16* __restrict__ whhh,
    float* __restrict__ cout)
{
  __shared__ unsigned wlds[1024 * 36];            // 147456 B
  __shared__ __align__(16) _Float16 hb[256];      // 512 B
  __shared__ float gbuf[512];                     // 2048 B
  const int tid = threadIdx.x;
  const int b = blockIdx.x;
  const int jloc = tid & 255;
  const int half = tid >> 8;
  const int rA = half * 256 + jloc;       // half0: i-row, half1: f-row
  const int rB = 512 + half * 256 + jloc; // half0: g-row, half1: o-row
  // stage LDS: dwords [92,128) of each row
  {
    const unsigned* wsrc = (const unsigned*)whhh;
    for (int idx = tid; idx < 1024 * 36; idx += 512) {
      int row = idx / 36, kp = idx - row * 36;
      wlds[row * 36 + kp] = wsrc[row * 128 + 92 + kp];
    }
  }
  if (tid < 256) hb[tid] = (_Float16)0.f;
  const uint4* pA = (const uint4*)(whhh + (size_t)rA * 256);
  const uint4* pB = (const uint4*)(whhh + (size_t)rB * 256);
  W12(DECLW)                              // dwords [0,48): resident
  const size_t bT = (size_t)b * 1024;
  const int rA36 = rA * 36, rB36 = rB * 36;
  float cst = 0.f;
  float xgA = xg3[bT * 1024 + rA];
  float xgB = xg3[bT * 1024 + rB];
  __syncthreads();
  for (int t = 0; t < 1024; ++t) {
    float nxA = 0.f, nxB = 0.f;
    if (t < 1023) {
      nxA = xg3[(bT + t + 1) * 1024 + rA];
      nxB = xg3[(bT + t + 1) * 1024 + rB];
    }
    float a0 = 0.f, a1 = 0.f, b0 = 0.f, b1 = 0.f;
    const float4* hb4 = (const float4*)hb;
    W12(DOTR)
    // compiler-level memory fence: forbids hoisting the streamed loads out
    // of the loop AND forbids remat of the resident loads across iterations.
    asm volatile("" ::: "memory");
    // streamed: dwords [48,92) -> 11 uint4 per row, re-read from L2 each step
#pragma unroll
    for (int j = 0; j < 11; ++j) {
      uint4 wa = pA[12 + j];
      uint4 wb = pB[12 + j];
      float4 h4 = hb4[12 + j];
      a0 = fdot2f(bcu(wa.x), bch(h4.x), a0); b0 = fdot2f(bcu(wb.x), bch(h4.x), b0);
      a1 = fdot2f(bcu(wa.y), bch(h4.y), a1); b1 = fdot2f(bcu(wb.y), bch(h4.y), b1);
      a0 = fdot2f(bcu(wa.z), bch(h4.z), a0); b0 = fdot2f(bcu(wb.z), bch(h4.z), b0);
      a1 = fdot2f(bcu(wa.w), bch(h4.w), a1); b1 = fdot2f(bcu(wb.w), bch(h4.w), b1);
    }
    // LDS section: dwords [92,128) -> 9 uint4 per row
#pragma unroll
    for (int j = 0; j < 9; ++j) {
      float4 h4 = hb4[23 + j];
      uint4 wa = *(const uint4*)&wlds[rA36 + 4 * j];
      uint4 wb = *(const uint4*)&wlds[rB36 + 4 * j];
      a0 = fdot2f(bcu(wa.x), bch(h4.x), a0); b0 = fdot2f(bcu(wb.x), bch(h4.x), b0);
      a1 = fdot2f(bcu(wa.y), bch(h4.y), a1); b1 = fdot2f(bcu(wb.y), bch(h4.y), b1);
      a0 = fdot2f(bcu(wa.z), bch(h4.z), a0); b0 = fdot2f(bcu(wb.z), bch(h4.z), b0);
      a1 = fdot2f(bcu(wa.w), bch(h4.w), a1); b1 = fdot2f(bcu(wb.w), bch(h4.w), b1);
    }
    float gA = a0 + a1 + xgA;   // half0: i-gate   half1: f-gate
    float gB = b0 + b1 + xgB;   // half0: g-gate   half1: o-gate
    if (half) { gbuf[jloc] = gA; gbuf[256 + jloc] = gB; }
    __syncthreads();
    if (!half) {
      float gf = gbuf[jloc], go = gbuf[256 + jloc];
      float si = 1.f / (1.f + __expf(-gA));
      float sf = 1.f / (1.f + __expf(-gf));
      float so = 1.f / (1.f + __expf(-go));
      float tg = 1.f - 2.f / (1.f + __expf(2.f * gB));
      cst = sf * cst + si * tg;
      float tc = 1.f - 2.f / (1.f + __expf(2.f * cst));
      float h = so * tc;
      cout[(bT + t) * 256 + jloc] = h;
      hb[jloc] = (_Float16)h;
    }
    __syncthreads();
    xgA = nxA; xgB = nxB;
  }
}

// ---------------- launch ----------------
extern "C" void kernel_launch(void* const* d_in, const int* in_sizes, int n_in,
                              void* d_out, int out_size, void* d_ws, size_t ws_size,
                              hipStream_t stream)
{
  const float* mels   = (const float*)d_in[0];
  const float* conv_w = (const float*)d_in[1];
  const float* ln_g   = (const float*)d_in[2];
  const float* ln_b   = (const float*)d_in[3];
  const float* w_hid  = (const float*)d_in[4];
  const float* w_out  = (const float*)d_in[5];
  const float* emb    = (const float*)d_in[6];
  const float* w_ih   = (const float*)d_in[7];
  const float* w_hh   = (const float*)d_in[8];
  const float* b_ih   = (const float*)d_in[9];
  const float* b_hh   = (const float*)d_in[10];

  float* out = (float*)d_out;
  float* q_out   = out;                 // [16,1024,64]
  float* c_out   = out + 1048576;       // [16,1024,256]
  float* z_out   = out + 5242880;       // [16,1024,64]
  float* loss_out = out + 6291456;
  float* perp_out = out + 6291457;

  char* ws = (char*)d_ws;
  float*  hA    = (float*)(ws + 0);            // 50331648 B (f32 activations)
  unsigned short* Ahi = (unsigned short*)(ws + 50331648);   // 25165824 B
  float*  xg3   = (float*)(ws + 50331648);     // alias Ahi (dead after ztail)
  char* wsw = ws + 117440512;
  float*    wT     = (float*)(wsw);                        // 983040 B
  _Float16* whhh   = (_Float16*)(wsw + 983040);            // 524288 B
  float*    wihT   = (float*)(wsw + 1507328);              // 262144 B
  float*    bias2  = (float*)(wsw + 1769472);              // 4096 B
  float*    esq    = (float*)(wsw + 1773568);              // 2048 B
  int*      counts = (int*)  (wsw + 1775616);              // 2048 B
  float*    lossrow= (float*)(wsw + 1777664);              // 65536 B
  unsigned short* Whi  = (unsigned short*)((char*)d_out + 4194304);
  unsigned short* Wzh  = (unsigned short*)((char*)d_out + 4194304 + 4718592);
  unsigned short* embh = (unsigned short*)((char*)d_out + 4194304 + 4718592 + 98304);
  if (ws_size < 119283712u) return;  // insufficient scratch: fail visibly

  prep_kernel<<<2248, 256, 0, stream>>>(conv_w, w_hh, w_ih, b_ih, b_hh, emb,
                                        wT, whhh, wihT, bias2, esq, counts);
  wcvt_kernel<<<9536, 256, 0, stream>>>(w_hid, w_out, emb, Whi, Wzh, embh);
  conv_kernel<<<3072, 256, 0, stream>>>(mels, wT, hA);
  for (int l = 0; l < 4; ++l) {
    ln_relu_kernel<<<16384, 256, 0, stream>>>(hA, Ahi, ln_g + l * 768, ln_b + l * 768);
    mlp_gemm<<<dim3(6, 128), 256, 0, stream>>>(
        Ahi, Whi + (size_t)l * 589824, hA);
  }
  ln_relu_kernel<<<16384, 256, 0, stream>>>(hA, Ahi, ln_g + 4 * 768, ln_b + 4 * 768);
  ztail_kernel<<<128, 256, 0, stream>>>(Ahi, Wzh, embh, esq, emb,
                                        z_out, q_out, counts, lossrow);
  finalize_kernel<<<1, 256, 0, stream>>>(lossrow, counts, loss_out, perp_out);
  xg_kernel<<<2048, 256, 0, stream>>>(q_out, wihT, bias2, xg3);
  lstm_kernel<<<16, 512, 0, stream>>>(xg3, whhh, c_out);
}

// Round 16
// 2129.560 us; speedup vs baseline: 4.2556x; 2.9864x over previous
//
#include <hip/hip_runtime.h>
#include <hip/hip_bf16.h>
#include <cstdint>

typedef _Float16 half2v __attribute__((ext_vector_type(2)));
typedef short bf16x8 __attribute__((ext_vector_type(8)));
typedef float f32x4v __attribute__((ext_vector_type(4)));

#define DI __device__ __forceinline__

DI half2v bch(float f)    { return __builtin_bit_cast(half2v, f); }
DI half2v bcu(unsigned u) { return __builtin_bit_cast(half2v, u); }

DI float fdot2f(half2v a, half2v b, float c) {
#if __has_builtin(__builtin_amdgcn_fdot2)
  return __builtin_amdgcn_fdot2(a, b, c, false);
#else
  return c + (float)a[0] * (float)b[0] + (float)a[1] * (float)b[1];
#endif
}

DI unsigned short bf16rne(float f) {
  unsigned u = __float_as_uint(f);
  unsigned r = (u + 0x7fffu + ((u >> 16) & 1u)) >> 16;
  return (unsigned short)r;
}

DI unsigned int ordbits(float f) {
  unsigned int u = __float_as_uint(f);
  return (u & 0x80000000u) ? ~u : (u | 0x80000000u);
}

// ---------------- block reduce (256 threads, 4 waves) ----------------
DI float blockReduceSum(float v, float* sbuf) {
  for (int off = 32; off; off >>= 1) v += __shfl_xor(v, off, 64);
  int wid = threadIdx.x >> 6;
  if ((threadIdx.x & 63) == 0) sbuf[wid] = v;
  __syncthreads();
  float r = sbuf[0] + sbuf[1] + sbuf[2] + sbuf[3];
  __syncthreads();
  return r;
}

// ---------------- prep: weight repack + zeroing ----------------
__global__ __launch_bounds__(256) void prep_kernel(
    const float* __restrict__ conv_w, const float* __restrict__ w_hh,
    const float* __restrict__ w_ih, const float* __restrict__ b_ih,
    const float* __restrict__ b_hh, const float* __restrict__ emb,
    float* __restrict__ wT, _Float16* __restrict__ whhh,
    float* __restrict__ wihT, float* __restrict__ bias2,
    float* __restrict__ esq, int* __restrict__ counts)
{
  int idx = blockIdx.x * 256 + threadIdx.x;
  if (idx < 245760) {
    int c = idx % 768, rest = idx / 768;          // rest = ci*4+k
    wT[idx] = conv_w[c * 320 + rest];
  }
  int i1 = idx - 245760;
  if (i1 >= 0 && i1 < 262144) whhh[i1] = (_Float16)w_hh[i1];
  int i2 = idx - (245760 + 262144);
  if (i2 >= 0 && i2 < 65536) {
    int d = i2 >> 10, grow = i2 & 1023;
    wihT[i2] = w_ih[grow * 64 + d];
  }
  int i3 = idx - (245760 + 262144 + 65536);
  if (i3 >= 0 && i3 < 1024) bias2[i3] = b_ih[i3] + b_hh[i3];
  int i4 = idx - (245760 + 262144 + 65536 + 1024);
  if (i4 >= 0 && i4 < 512) {
    float s = 0.f;
    for (int d = 0; d < 64; ++d) { float v = emb[i4 * 64 + d]; s += v * v; }
    esq[i4] = s;
  }
  int i5 = idx - (245760 + 262144 + 65536 + 1024 + 512);
  if (i5 >= 0 && i5 < 512) counts[i5] = 0;
}

// ---------------- convert weights to bf16 (hi only) ----------------
__global__ __launch_bounds__(256) void wcvt_kernel(
    const float* __restrict__ w_hid, const float* __restrict__ w_out,
    const float* __restrict__ emb, unsigned short* __restrict__ Whi,
    unsigned short* __restrict__ Wzh, unsigned short* __restrict__ embh)
{
  int idx = blockIdx.x * 256 + threadIdx.x;
  if (idx < 2359296) Whi[idx] = bf16rne(w_hid[idx]);
  int i1 = idx - 2359296;
  if (i1 >= 0 && i1 < 49152) Wzh[i1] = bf16rne(w_out[i1]);
  int i2 = idx - (2359296 + 49152);
  if (i2 >= 0 && i2 < 32768) embh[i2] = bf16rne(emb[i2]);
}

// ---------------- conv1d k=4 s=2 p=1 as tiled GEMM-ish ----------------
__global__ __launch_bounds__(256) void conv_kernel(
    const float* __restrict__ mels, const float* __restrict__ wT,
    float* __restrict__ out)
{
  __shared__ float xs[80][68];
  const int bx = blockIdx.x;
  const int cblk = bx % 6;
  const int rb = bx / 6;
  const int b = rb >> 5;
  const int t0 = (rb & 31) << 5;
  const int tid = threadIdx.x;
  const int g0 = 2 * t0 - 1;
  for (int e = tid; e < 80 * 68; e += 256) {
    int ci = e / 68, ix = e % 68;
    int g = g0 + ix;
    float v = 0.f;
    if (ix < 67 && g >= 0 && g < 2048) v = mels[((size_t)b * 80 + ci) * 2048 + g];
    xs[ci][ix] = v;
  }
  __syncthreads();
  const int tc = tid & 31, tt = tid >> 5;
  const int c = cblk * 128 + tc * 4;
  float acc[4][4] = {};
  for (int ci = 0; ci < 80; ++ci) {
    float m[10];
#pragma unroll
    for (int r = 0; r < 10; ++r) m[r] = xs[ci][tt * 8 + r];
#pragma unroll
    for (int k = 0; k < 4; ++k) {
      float4 wv = *(const float4*)&wT[(size_t)(ci * 4 + k) * 768 + c];
#pragma unroll
      for (int i = 0; i < 4; ++i) {
        float mv = m[2 * i + k];
        acc[i][0] += mv * wv.x; acc[i][1] += mv * wv.y;
        acc[i][2] += mv * wv.z; acc[i][3] += mv * wv.w;
      }
    }
  }
#pragma unroll
  for (int i = 0; i < 4; ++i) {
    int tp = t0 + tt * 4 + i;
    float4 v = make_float4(acc[i][0], acc[i][1], acc[i][2], acc[i][3]);
    *(float4*)&out[((size_t)b * 1024 + tp) * 768 + c] = v;
  }
}

// ---------------- LayerNorm + ReLU -> bf16 (hi only) ----------------
__global__ __launch_bounds__(256) void ln_relu_kernel(
    const float* __restrict__ in, unsigned short* __restrict__ ohi,
    const float* __restrict__ gamma, const float* __restrict__ beta)
{
  __shared__ float sbuf[4];
  const int row = blockIdx.x, tid = threadIdx.x;
  const float* p = in + (size_t)row * 768;
  float v0 = p[tid], v1 = p[tid + 256], v2 = p[tid + 512];
  float s = blockReduceSum(v0 + v1 + v2, sbuf);
  float mean = s * (1.f / 768.f);
  float d0 = v0 - mean, d1 = v1 - mean, d2 = v2 - mean;
  float sq = blockReduceSum(d0 * d0 + d1 * d1 + d2 * d2, sbuf);
  float rstd = rsqrtf(sq * (1.f / 768.f) + 1e-5f);
  float y0 = fmaxf(d0 * rstd * gamma[tid]       + beta[tid],       0.f);
  float y1 = fmaxf(d1 * rstd * gamma[tid + 256] + beta[tid + 256], 0.f);
  float y2 = fmaxf(d2 * rstd * gamma[tid + 512] + beta[tid + 512], 0.f);
  unsigned short* qh = ohi + (size_t)row * 768;
  qh[tid] = bf16rne(y0); qh[tid + 256] = bf16rne(y1); qh[tid + 512] = bf16rne(y2);
}

// ---------------- bf16 MFMA GEMM: C = A W^T (hi only) -----------------------
__global__ __launch_bounds__(256) void mlp_gemm(
    const unsigned short* __restrict__ Ah, const unsigned short* __restrict__ Wh,
    float* __restrict__ C)
{
  __shared__ unsigned short As[128][40];   // 32 used + 8 pad (16B-aligned rows)
  __shared__ unsigned short Bs[128][40];
  const int tid = threadIdx.x;
  const int lane = tid & 63, wid = tid >> 6;
  const int wm = wid >> 1, wn = wid & 1;
  const int l15 = lane & 15, kg = lane >> 4;
  const size_t row0 = (size_t)blockIdx.y * 128;
  const int col0 = blockIdx.x * 128;
  f32x4v acc[4][4];
#pragma unroll
  for (int i = 0; i < 4; ++i)
#pragma unroll
    for (int j = 0; j < 4; ++j) acc[i][j] = (f32x4v){0.f, 0.f, 0.f, 0.f};
  for (int kt = 0; kt < 768; kt += 32) {
    __syncthreads();   // guard LDS overwrite vs previous iteration reads
#pragma unroll
    for (int it = 0; it < 2; ++it) {
      int sidx = tid + it * 256;           // 512 slots of 8 bf16 per tile
      int r = sidx >> 2, kc = (sidx & 3) << 3;
      *(uint4*)&As[r][kc] = *(const uint4*)&Ah[(row0 + r) * 768 + kt + kc];
      *(uint4*)&Bs[r][kc] = *(const uint4*)&Wh[(size_t)(col0 + r) * 768 + kt + kc];
    }
    __syncthreads();
    bf16x8 af[4], bfr[4];
#pragma unroll
    for (int mf = 0; mf < 4; ++mf)
      af[mf] = *(const bf16x8*)&As[wm * 64 + mf * 16 + l15][kg * 8];
#pragma unroll
    for (int nf = 0; nf < 4; ++nf)
      bfr[nf] = *(const bf16x8*)&Bs[wn * 64 + nf * 16 + l15][kg * 8];
#pragma unroll
    for (int mf = 0; mf < 4; ++mf)
#pragma unroll
      for (int nf = 0; nf < 4; ++nf)
        acc[mf][nf] = __builtin_amdgcn_mfma_f32_16x16x32_bf16(
            af[mf], bfr[nf], acc[mf][nf], 0, 0, 0);
  }
#pragma unroll
  for (int mf = 0; mf < 4; ++mf)
#pragma unroll
    for (int nf = 0; nf < 4; ++nf)
#pragma unroll
      for (int r = 0; r < 4; ++r)
        C[(row0 + wm * 64 + mf * 16 + kg * 4 + r) * 768 +
          col0 + wn * 64 + nf * 16 + l15] = acc[mf][nf][r];
}

// ---------------- fused tail: z = A4 @ Wz^T, dots vs emb, argmin, quant -----
__global__ __launch_bounds__(256) void ztail_kernel(
    const unsigned short* __restrict__ A4h, const unsigned short* __restrict__ Wzh,
    const unsigned short* __restrict__ embh, const float* __restrict__ esq,
    const float* __restrict__ emb, float* __restrict__ z_out,
    float* __restrict__ quant, int* __restrict__ counts,
    float* __restrict__ lossrow)
{
  __shared__ unsigned short As[128][40];            // 10240 B
  __shared__ unsigned short Ws[64][40];             // 5120 B
  __shared__ unsigned short zh[128][88];            // 22528 B
  __shared__ float zf[128][68];                     // 34816 B
  __shared__ unsigned short embs[128][88];          // 22528 B
  __shared__ unsigned long long best2[2][128];      // 2048 B
  __shared__ float esqs[512];                       // 2048 B
  const int tid = threadIdx.x;
  const int lane = tid & 63, wid = tid >> 6;
  const int wm = wid >> 1, wn = wid & 1;
  const int l15 = lane & 15, kg = lane >> 4;
  const size_t row0 = (size_t)blockIdx.x * 128;
  for (int i = tid; i < 512; i += 256) esqs[i] = esq[i];
  f32x4v zacc[4][2];
#pragma unroll
  for (int i = 0; i < 4; ++i)
#pragma unroll
    for (int j = 0; j < 2; ++j) zacc[i][j] = (f32x4v){0.f, 0.f, 0.f, 0.f};
  for (int kt = 0; kt < 768; kt += 32) {
    __syncthreads();
#pragma unroll
    for (int it = 0; it < 2; ++it) {
      int sidx = tid + it * 256;
      int r = sidx >> 2, kc = (sidx & 3) << 3;
      *(uint4*)&As[r][kc] = *(const uint4*)&A4h[(row0 + r) * 768 + kt + kc];
    }
    { int r = tid >> 2, kc = (tid & 3) << 3;
      *(uint4*)&Ws[r][kc] = *(const uint4*)&Wzh[r * 768 + kt + kc]; }
    __syncthreads();
    bf16x8 af[4], bfr[2];
#pragma unroll
    for (int mf = 0; mf < 4; ++mf)
      af[mf] = *(const bf16x8*)&As[wm * 64 + mf * 16 + l15][kg * 8];
#pragma unroll
    for (int nf = 0; nf < 2; ++nf)
      bfr[nf] = *(const bf16x8*)&Ws[wn * 32 + nf * 16 + l15][kg * 8];
#pragma unroll
    for (int mf = 0; mf < 4; ++mf)
#pragma unroll
      for (int nf = 0; nf < 2; ++nf)
        zacc[mf][nf] = __builtin_amdgcn_mfma_f32_16x16x32_bf16(
            af[mf], bfr[nf], zacc[mf][nf], 0, 0, 0);
  }
#pragma unroll
  for (int mf = 0; mf < 4; ++mf)
#pragma unroll
    for (int nf = 0; nf < 2; ++nf)
#pragma unroll
      for (int r = 0; r < 4; ++r) {
        float v = zacc[mf][nf][r];
        int rr = wm * 64 + mf * 16 + kg * 4 + r;
        int cc = wn * 32 + nf * 16 + l15;
        zf[rr][cc] = v;
        zh[rr][cc] = bf16rne(v);
        z_out[(row0 + rr) * 64 + cc] = v;
      }
  if (tid < 128) { best2[0][tid] = ~0ull; best2[1][tid] = ~0ull; }
  __syncthreads();
  for (int c0 = 0; c0 < 512; c0 += 128) {
    __syncthreads();
#pragma unroll
    for (int ii = 0; ii < 4; ++ii) {
      int s = tid * 4 + ii;
      int code = s >> 3, k = (s & 7) << 3;
      *(uint4*)&embs[code][k] = *(const uint4*)&embh[(size_t)(c0 + code) * 64 + k];
    }
    __syncthreads();
    bf16x8 af2[4][2], bf2[4][2];
#pragma unroll
    for (int mf = 0; mf < 4; ++mf)
#pragma unroll
      for (int kk = 0; kk < 2; ++kk)
        af2[mf][kk] = *(const bf16x8*)&zh[wm * 64 + mf * 16 + l15][kk * 32 + kg * 8];
#pragma unroll
    for (int nf = 0; nf < 4; ++nf)
#pragma unroll
      for (int kk = 0; kk < 2; ++kk)
        bf2[nf][kk] = *(const bf16x8*)&embs[wn * 64 + nf * 16 + l15][kk * 32 + kg * 8];
#pragma unroll
    for (int mf = 0; mf < 4; ++mf) {
      f32x4v dacc[4];
#pragma unroll
      for (int nf = 0; nf < 4; ++nf) {
        dacc[nf] = (f32x4v){0.f, 0.f, 0.f, 0.f};
        dacc[nf] = __builtin_amdgcn_mfma_f32_16x16x32_bf16(
            af2[mf][0], bf2[nf][0], dacc[nf], 0, 0, 0);
        dacc[nf] = __builtin_amdgcn_mfma_f32_16x16x32_bf16(
            af2[mf][1], bf2[nf][1], dacc[nf], 0, 0, 0);
      }
      unsigned long long rb0 = ~0ull, rb1 = ~0ull, rb2 = ~0ull, rb3 = ~0ull;
#pragma unroll
      for (int nf = 0; nf < 4; ++nf) {
        int code = c0 + wn * 64 + nf * 16 + l15;
        float ev = esqs[code];
        unsigned long long k0 = ((unsigned long long)ordbits(ev - 2.f * dacc[nf][0]) << 32) | (unsigned)code;
        unsigned long long k1 = ((unsigned long long)ordbits(ev - 2.f * dacc[nf][1]) << 32) | (unsigned)code;
        unsigned long long k2 = ((unsigned long long)ordbits(ev - 2.f * dacc[nf][2]) << 32) | (unsigned)code;
        unsigned long long k3 = ((unsigned long long)ordbits(ev - 2.f * dacc[nf][3]) << 32) | (unsigned)code;
        rb0 = k0 < rb0 ? k0 : rb0;  rb1 = k1 < rb1 ? k1 : rb1;
        rb2 = k2 < rb2 ? k2 : rb2;  rb3 = k3 < rb3 ? k3 : rb3;
      }
#pragma unroll
      for (int m = 1; m < 16; m <<= 1) {
        unsigned long long o;
        o = __shfl_xor(rb0, m, 64); rb0 = o < rb0 ? o : rb0;
        o = __shfl_xor(rb1, m, 64); rb1 = o < rb1 ? o : rb1;
        o = __shfl_xor(rb2, m, 64); rb2 = o < rb2 ? o : rb2;
        o = __shfl_xor(rb3, m, 64); rb3 = o < rb3 ? o : rb3;
      }
      if (l15 == 0) {
        int rbase = wm * 64 + mf * 16 + kg * 4;
        unsigned long long c;
        c = best2[wn][rbase + 0]; best2[wn][rbase + 0] = rb0 < c ? rb0 : c;
        c = best2[wn][rbase + 1]; best2[wn][rbase + 1] = rb1 < c ? rb1 : c;
        c = best2[wn][rbase + 2]; best2[wn][rbase + 2] = rb2 < c ? rb2 : c;
        c = best2[wn][rbase + 3]; best2[wn][rbase + 3] = rb3 < c ? rb3 : c;
      }
    }
  }
  __syncthreads();
  if (tid < 128) {
    unsigned long long a = best2[0][tid], b = best2[1][tid];
    best2[0][tid] = b < a ? b : a;
  }
  __syncthreads();
  {
    int rr = tid >> 1, hf = tid & 1;
    int bi = (int)(best2[0][rr] & 0xffffffffu);
    float ls = 0.f;
#pragma unroll
    for (int dd = 0; dd < 32; ++dd) {
      int d = hf * 32 + dd;
      float e = emb[(size_t)bi * 64 + d];
      quant[(row0 + rr) * 64 + d] = e;
      float df = zf[rr][d] - e;
      ls += df * df;
    }
    ls += __shfl_xor(ls, 1, 64);
    if (hf == 0) {
      lossrow[row0 + rr] = ls;
      atomicAdd(&counts[bi], 1);
    }
  }
}

// ---------------- loss + perplexity ----------------
__global__ __launch_bounds__(256) void finalize_kernel(
    const float* __restrict__ lossrow, const int* __restrict__ counts,
    float* __restrict__ loss_out, float* __restrict__ perp_out)
{
  __shared__ float sbuf[4];
  const int tid = threadIdx.x;
  float s = 0.f;
  for (int i = tid; i < 16384; i += 256) s += lossrow[i];
  s = blockReduceSum(s, sbuf);
  float t = 0.f;
  for (int e = tid; e < 512; e += 256) {
    float p = (float)counts[e] * (1.f / 16384.f);
    t += p * logf(p + 1e-10f);
  }
  t = blockReduceSum(t, sbuf);
  if (tid == 0) {
    *loss_out = 0.25f * s / (16384.f * 64.f);
    *perp_out = expf(-t);
  }
}

// ---------------- xg3[b][t][1024 gates natural order] = q @ w_ih^T + biases ---
__global__ __launch_bounds__(256) void xg_kernel(
    const float* __restrict__ q, const float* __restrict__ wihT,
    const float* __restrict__ bias2, float* __restrict__ xg3)
{
  __shared__ float qs[8][64];
  const int r0 = blockIdx.x * 8, tid = threadIdx.x;
  for (int e = tid; e < 512; e += 256)
    qs[e >> 6][e & 63] = q[(size_t)r0 * 64 + e];
  __syncthreads();
  float4 bias = *(const float4*)&bias2[tid * 4];
  float4 acc[8];
#pragma unroll
  for (int r = 0; r < 8; ++r) acc[r] = bias;
  for (int d = 0; d < 64; ++d) {
    float4 wv = *(const float4*)&wihT[d * 1024 + tid * 4];
#pragma unroll
    for (int r = 0; r < 8; ++r) {
      float qv = qs[r][d];
      acc[r].x += qv * wv.x; acc[r].y += qv * wv.y;
      acc[r].z += qv * wv.z; acc[r].w += qv * wv.w;
    }
  }
#pragma unroll
  for (int r = 0; r < 8; ++r)
    *(float4*)&xg3[(size_t)(r0 + r) * 1024 + tid * 4] = acc[r];
}

// ---------------- LSTM: EXACT R13 config (best measured: 1600us steady) -----
// Mechanism ledger (R4-R15, all alternatives measured worse):
//   - named-var residency capped at 128 VGPR by allocator (R9)
//   - LICM hoists streamed loads -> spill-stream at 1600us steady (R13) [BEST]
//   - no-restrict aliasing: store->load serialization, 8.5us/step (R14)
//   - asm memory clobber: issue-barrier serialization, 5.8us/step (R15)
//   - opaque pointer: broken addressing, 4.0us/step (R7)
// The 32ms scratch first-touch hits only the first (untimed) launch.
// LSTM floor = serial 1024-step dependency x 16-CU occupancy; latency-bound.
#define W12(M) M(0) M(1) M(2) M(3) M(4) M(5) M(6) M(7) M(8) M(9) M(10) M(11)
#define DECLW(J) uint4 wa##J = pA[J]; uint4 wb##J = pB[J];
#define DOTR(J) { float4 h4 = hb4[J]; \
  a0 = fdot2f(bcu(wa##J.x), bch(h4.x), a0); b0 = fdot2f(bcu(wb##J.x), bch(h4.x), b0); \
  a1 = fdot2f(bcu(wa##J.y), bch(h4.y), a1); b1 = fdot2f(bcu(wb##J.y), bch(h4.y), b1); \
  a0 = fdot2f(bcu(wa##J.z), bch(h4.z), a0); b0 = fdot2f(bcu(wb##J.z), bch(h4.z), b0); \
  a1 = fdot2f(bcu(wa##J.w), bch(h4.w), a1); b1 = fdot2f(bcu(wb##J.w), bch(h4.w), b1); }

__global__
__attribute__((amdgpu_flat_work_group_size(512, 512), amdgpu_waves_per_eu(2, 2)))
void lstm_kernel(
    const float* __restrict__ xg3, const _Float16* __restrict__ whhh,
    float* __restrict__ cout)
{
  __shared__ unsigned wlds[1024 * 36];            // 147456 B
  __shared__ __align__(16) _Float16 hb[256];      // 512 B
  __shared__ float gbuf[512];                     // 2048 B
  const int tid = threadIdx.x;
  const int b = blockIdx.x;
  const int jloc = tid & 255;
  const int half = tid >> 8;
  const int rA = half * 256 + jloc;       // half0: i-row, half1: f-row
  const int rB = 512 + half * 256 + jloc; // half0: g-row, half1: o-row
  // stage LDS: dwords [92,128) of each row
  {
    const unsigned* wsrc = (const unsigned*)whhh;
    for (int idx = tid; idx < 1024 * 36; idx += 512) {
      int row = idx / 36, kp = idx - row * 36;
      wlds[row * 36 + kp] = wsrc[row * 128 + 92 + kp];
    }
  }
  if (tid < 256) hb[tid] = (_Float16)0.f;
  const uint4* pA = (const uint4*)(whhh + (size_t)rA * 256);
  const uint4* pB = (const uint4*)(whhh + (size_t)rB * 256);
  W12(DECLW)                              // dwords [0,48)
  const size_t bT = (size_t)b * 1024;
  const int rA36 = rA * 36, rB36 = rB * 36;
  float cst = 0.f;
  float xgA = xg3[bT * 1024 + rA];
  float xgB = xg3[bT * 1024 + rB];
  __syncthreads();
  for (int t = 0; t < 1024; ++t) {
    float nxA = 0.f, nxB = 0.f;
    if (t < 1023) {
      nxA = xg3[(bT + t + 1) * 1024 + rA];
      nxB = xg3[(bT + t + 1) * 1024 + rB];
    }
    float a0 = 0.f, a1 = 0.f, b0 = 0.f, b1 = 0.f;
    const float4* hb4 = (const float4*)hb;
    W12(DOTR)
    // dwords [48,92) -> 11 uint4 per row (compiler hoists+spills; the spill
    // re-stream at 1600us/launch measured FASTER than every anti-hoist tool)
#pragma unroll
    for (int j = 0; j < 11; ++j) {
      uint4 wa = pA[12 + j];
      uint4 wb = pB[12 + j];
      float4 h4 = hb4[12 + j];
      a0 = fdot2f(bcu(wa.x), bch(h4.x), a0); b0 = fdot2f(bcu(wb.x), bch(h4.x), b0);
      a1 = fdot2f(bcu(wa.y), bch(h4.y), a1); b1 = fdot2f(bcu(wb.y), bch(h4.y), b1);
      a0 = fdot2f(bcu(wa.z), bch(h4.z), a0); b0 = fdot2f(bcu(wb.z), bch(h4.z), b0);
      a1 = fdot2f(bcu(wa.w), bch(h4.w), a1); b1 = fdot2f(bcu(wb.w), bch(h4.w), b1);
    }
    // LDS section: dwords [92,128) -> 9 uint4 per row
#pragma unroll
    for (int j = 0; j < 9; ++j) {
      float4 h4 = hb4[23 + j];
      uint4 wa = *(const uint4*)&wlds[rA36 + 4 * j];
      uint4 wb = *(const uint4*)&wlds[rB36 + 4 * j];
      a0 = fdot2f(bcu(wa.x), bch(h4.x), a0); b0 = fdot2f(bcu(wb.x), bch(h4.x), b0);
      a1 = fdot2f(bcu(wa.y), bch(h4.y), a1); b1 = fdot2f(bcu(wb.y), bch(h4.y), b1);
      a0 = fdot2f(bcu(wa.z), bch(h4.z), a0); b0 = fdot2f(bcu(wb.z), bch(h4.z), b0);
      a1 = fdot2f(bcu(wa.w), bch(h4.w), a1); b1 = fdot2f(bcu(wb.w), bch(h4.w), b1);
    }
    float gA = a0 + a1 + xgA;   // half0: i-gate   half1: f-gate
    float gB = b0 + b1 + xgB;   // half0: g-gate   half1: o-gate
    if (half) { gbuf[jloc] = gA; gbuf[256 + jloc] = gB; }
    __syncthreads();
    if (!half) {
      float gf = gbuf[jloc], go = gbuf[256 + jloc];
      float si = 1.f / (1.f + __expf(-gA));
      float sf = 1.f / (1.f + __expf(-gf));
      float so = 1.f / (1.f + __expf(-go));
      float tg = 1.f - 2.f / (1.f + __expf(2.f * gB));
      cst = sf * cst + si * tg;
      float tc = 1.f - 2.f / (1.f + __expf(2.f * cst));
      float h = so * tc;
      cout[(bT + t) * 256 + jloc] = h;
      hb[jloc] = (_Float16)h;
    }
    __syncthreads();
    xgA = nxA; xgB = nxB;
  }
}

// ---------------- launch ----------------
extern "C" void kernel_launch(void* const* d_in, const int* in_sizes, int n_in,
                              void* d_out, int out_size, void* d_ws, size_t ws_size,
                              hipStream_t stream)
{
  const float* mels   = (const float*)d_in[0];
  const float* conv_w = (const float*)d_in[1];
  const float* ln_g   = (const float*)d_in[2];
  const float* ln_b   = (const float*)d_in[3];
  const float* w_hid  = (const float*)d_in[4];
  const float* w_out  = (const float*)d_in[5];
  const float* emb    = (const float*)d_in[6];
  const float* w_ih   = (const float*)d_in[7];
  const float* w_hh   = (const float*)d_in[8];
  const float* b_ih   = (const float*)d_in[9];
  const float* b_hh   = (const float*)d_in[10];

  float* out = (float*)d_out;
  float* q_out   = out;                 // [16,1024,64]
  float* c_out   = out + 1048576;       // [16,1024,256]
  float* z_out   = out + 5242880;       // [16,1024,64]
  float* loss_out = out + 6291456;
  float* perp_out = out + 6291457;

  char* ws = (char*)d_ws;
  float*  hA    = (float*)(ws + 0);            // 50331648 B (f32 activations)
  unsigned short* Ahi = (unsigned short*)(ws + 50331648);   // 25165824 B
  float*  xg3   = (float*)(ws + 50331648);     // alias Ahi (dead after ztail)
  char* wsw = ws + 117440512;
  float*    wT     = (float*)(wsw);                        // 983040 B
  _Float16* whhh   = (_Float16*)(wsw + 983040);            // 524288 B
  float*    wihT   = (float*)(wsw + 1507328);              // 262144 B
  float*    bias2  = (float*)(wsw + 1769472);              // 4096 B
  float*    esq    = (float*)(wsw + 1773568);              // 2048 B
  int*      counts = (int*)  (wsw + 1775616);              // 2048 B
  float*    lossrow= (float*)(wsw + 1777664);              // 65536 B
  unsigned short* Whi  = (unsigned short*)((char*)d_out + 4194304);
  unsigned short* Wzh  = (unsigned short*)((char*)d_out + 4194304 + 4718592);
  unsigned short* embh = (unsigned short*)((char*)d_out + 4194304 + 4718592 + 98304);
  if (ws_size < 119283712u) return;  // insufficient scratch: fail visibly

  prep_kernel<<<2248, 256, 0, stream>>>(conv_w, w_hh, w_ih, b_ih, b_hh, emb,
                                        wT, whhh, wihT, bias2, esq, counts);
  wcvt_kernel<<<9536, 256, 0, stream>>>(w_hid, w_out, emb, Whi, Wzh, embh);
  conv_kernel<<<3072, 256, 0, stream>>>(mels, wT, hA);
  for (int l = 0; l < 4; ++l) {
    ln_relu_kernel<<<16384, 256, 0, stream>>>(hA, Ahi, ln_g + l * 768, ln_b + l * 768);
    mlp_gemm<<<dim3(6, 128), 256, 0, stream>>>(
        Ahi, Whi + (size_t)l * 589824, hA);
  }
  ln_relu_kernel<<<16384, 256, 0, stream>>>(hA, Ahi, ln_g + 4 * 768, ln_b + 4 * 768);
  ztail_kernel<<<128, 256, 0, stream>>>(Ahi, Wzh, embh, esq, emb,
                                        z_out, q_out, counts, lossrow);
  finalize_kernel<<<1, 256, 0, stream>>>(lossrow, counts, loss_out, perp_out);
  xg_kernel<<<2048, 256, 0, stream>>>(q_out, wihT, bias2, xg3);
  lstm_kernel<<<16, 512, 0, stream>>>(xg3, whhh, c_out);
}